// Round 1
// 430.078 us; speedup vs baseline: 1.0366x; 1.0366x over previous
//
#include <hip/hip_runtime.h>

#define N_NODES 8192
#define FDIM 128
#define NEG_SLOPE 0.2f
#define SEG 512   // per-wave neighbor capacity (mean ~102, huge headroom)

// ---------------- Kernel A: Wh = h @ W.T (fp32) + colsum S ----------------
__global__ __launch_bounds__(256) void wh_fused_kernel(
    const float* __restrict__ h, const float* __restrict__ W,
    float* __restrict__ Wh, float* __restrict__ S) {
  __shared__ float Wt[FDIM * 132];   // Wt[k*132+o] = W[o][k]
  __shared__ float rows[32 * 132];   // rows[r*132+k]; reused as colsum scratch
  const int t = threadIdx.x;
  const int base = blockIdx.x * 32;
  for (int it = 0; it < 64; ++it) {
    int idx = t + 256 * it;          // idx = o*128+k
    int o = idx >> 7, k = idx & 127;
    Wt[k * 132 + o] = W[idx];
  }
  for (int it = 0; it < 16; ++it) {
    int idx = t + 256 * it;          // idx = r*128+col
    int r = idx >> 7, col = idx & 127;
    rows[r * 132 + col] = h[(size_t)base * FDIM + idx];
  }
  __syncthreads();
  const int c4 = (t & 31) * 4;
  const int g = t >> 5;
  float acc[4][4];
#pragma unroll
  for (int rr = 0; rr < 4; ++rr)
#pragma unroll
    for (int cc = 0; cc < 4; ++cc) acc[rr][cc] = 0.f;
  for (int k = 0; k < FDIM; ++k) {
    float4 wv = *(const float4*)&Wt[k * 132 + c4];
    float rv[4];
#pragma unroll
    for (int rr = 0; rr < 4; ++rr) rv[rr] = rows[(4 * g + rr) * 132 + k];
#pragma unroll
    for (int rr = 0; rr < 4; ++rr) {
      acc[rr][0] += rv[rr] * wv.x;
      acc[rr][1] += rv[rr] * wv.y;
      acc[rr][2] += rv[rr] * wv.z;
      acc[rr][3] += rv[rr] * wv.w;
    }
  }
#pragma unroll
  for (int rr = 0; rr < 4; ++rr) {
    int r = base + 4 * g + rr;
    *(float4*)&Wh[(size_t)r * FDIM + c4] =
        make_float4(acc[rr][0], acc[rr][1], acc[rr][2], acc[rr][3]);
  }
  __syncthreads();
  float4 cs = make_float4(acc[0][0] + acc[1][0] + acc[2][0] + acc[3][0],
                          acc[0][1] + acc[1][1] + acc[2][1] + acc[3][1],
                          acc[0][2] + acc[1][2] + acc[2][2] + acc[3][2],
                          acc[0][3] + acc[1][3] + acc[2][3] + acc[3][3]);
  *(float4*)&rows[g * FDIM + c4] = cs;
  __syncthreads();
  if (t < FDIM) {
    float s = 0.f;
#pragma unroll
    for (int gg = 0; gg < 8; ++gg) s += rows[gg * FDIM + t];
    atomicAdd(&S[t], s);
  }
}

// ---------------- Kernel C1: s1 = Wh@a1, s2 = Wh@a2 ----------------
__global__ __launch_bounds__(256) void scores_kernel(
    const float* __restrict__ Wh, const float* __restrict__ a,
    float* __restrict__ s1, float* __restrict__ s2) {
  const int t = threadIdx.x;
  const int lane = t & 63;
  const int wave = t >> 6;
  const int row = blockIdx.x * 4 + wave;
  float v0 = Wh[(size_t)row * FDIM + lane];
  float v1 = Wh[(size_t)row * FDIM + 64 + lane];
  float d1 = v0 * a[lane] + v1 * a[64 + lane];
  float d2 = v0 * a[FDIM + lane] + v1 * a[FDIM + 64 + lane];
  for (int off = 32; off; off >>= 1) {
    d1 += __shfl_down(d1, off);
    d2 += __shfl_down(d2, off);
  }
  if (lane == 0) { s1[row] = d1; s2[row] = d2; }
}

// non-temporal float4 load: adj is streamed exactly once — keep it out of
// the L2 working set so Wh (4 MB) stays resident for the gather phase.
__device__ __forceinline__ float4 ntload4(const float4* p) {
  typedef float f4v __attribute__((ext_vector_type(4)));
  f4v v = __builtin_nontemporal_load((const f4v*)p);
  return make_float4(v[0], v[1], v[2], v[3]);
}

// ---------------- Kernel B: per-row softmax + sparse gather ----------------
// one block (4 waves) per row i.
// scan:   adj ONLY. 8 float4 loads FORCED in flight (asm keep-alive +
//         sched_barrier; launch_bounds(256,4) gives the 128-VGPR budget —
//         previous build was squeezed to 24 VGPR and serialized the loads,
//         capping HBM at 1.9 TB/s). ballot+mbcnt compaction into LDS.
// phase2: e = leakyrelu(s1i + s2[j]) via random 4B gathers (L1-hot), wave max.
// phase3: p = exp(e-m) once per pair, wave sum.   (no cross-wave barrier:
//         each wave touches only its own segment)
// gather: half-wave per pair, float4 Wh loads, 4-deep unroll.
__global__ __launch_bounds__(256, 4) void gat_row_kernel(
    const float* __restrict__ adj, const float* __restrict__ Wh,
    const float* __restrict__ s1, const float* __restrict__ s2,
    const float* __restrict__ S, float* __restrict__ out) {
  const int i = blockIdx.x;
  const int t = threadIdx.x;
  const int lane = t & 63;
  const int wave = t >> 6;
  __shared__ float2 pairs[4 * SEG];  // .x = e then p ; .y = j (int bits)
  __shared__ int counts[4];
  __shared__ float red[4];           // per-wave max
  __shared__ float red2[4];          // per-wave exp-sum
  __shared__ float fpart[4][FDIM];

  const float s1i = s1[i];
  const float4* __restrict__ arow = (const float4*)(adj + (size_t)i * N_NODES);
  float2* __restrict__ mypairs = pairs + wave * SEG;
  const unsigned long long lmask = (1ull << lane) - 1ull;

  // ---- scan: all 8 row-chunks in flight, index-only compaction ----
  float4 av[8];
#pragma unroll
  for (int it = 0; it < 8; ++it) av[it] = ntload4(&arow[it * 256 + t]);
  // single asm naming every loaded component: forces all 8 dwordx4 loads to
  // be issued (and completed) before any ballot processing — the compiler
  // cannot re-serialize them to save registers.
  asm volatile("" ::
      "v"(av[0].x), "v"(av[0].y), "v"(av[0].z), "v"(av[0].w),
      "v"(av[1].x), "v"(av[1].y), "v"(av[1].z), "v"(av[1].w),
      "v"(av[2].x), "v"(av[2].y), "v"(av[2].z), "v"(av[2].w),
      "v"(av[3].x), "v"(av[3].y), "v"(av[3].z), "v"(av[3].w),
      "v"(av[4].x), "v"(av[4].y), "v"(av[4].z), "v"(av[4].w),
      "v"(av[5].x), "v"(av[5].y), "v"(av[5].z), "v"(av[5].w),
      "v"(av[6].x), "v"(av[6].y), "v"(av[6].z), "v"(av[6].w),
      "v"(av[7].x), "v"(av[7].y), "v"(av[7].z), "v"(av[7].w));
  __builtin_amdgcn_sched_barrier(0);
  int cbase = 0;
#pragma unroll
  for (int it = 0; it < 8; ++it) {
    const int j4 = it * 256 + t;
    float v[4] = {av[it].x, av[it].y, av[it].z, av[it].w};
#pragma unroll
    for (int c = 0; c < 4; ++c) {
      bool pred = (v[c] != 0.f);
      unsigned long long b = __ballot(pred);
      if (pred) {
        int pos = cbase + (int)__popcll(b & lmask);
        if (pos < SEG) ((int*)&mypairs[pos])[1] = j4 * 4 + c;
      }
      cbase += (int)__popcll(b);
    }
  }
  const int mycnt = cbase < SEG ? cbase : SEG;
  if (lane == 0) counts[wave] = mycnt;

  // ---- phase2: e from s2[j] gathers, wave max ----
  float lmax = -1e30f;
  for (int k = lane; k < mycnt; k += 64) {
    int j = ((const int*)&mypairs[k])[1];
    float e = s1i + s2[j];
    e = e > 0.f ? e : NEG_SLOPE * e;
    mypairs[k].x = e;
    lmax = fmaxf(lmax, e);
  }
  for (int off = 32; off; off >>= 1) lmax = fmaxf(lmax, __shfl_down(lmax, off));
  if (lane == 0) red[wave] = lmax;
  __syncthreads();
  const int cnt = counts[0] + counts[1] + counts[2] + counts[3];
  float m = fmaxf(fmaxf(red[0], red[1]), fmaxf(red[2], red[3]));
  if (cnt < N_NODES) m = fmaxf(m, 0.f);  // adj==0 entries contribute z=0
  const float em = __expf(-m);

  // ---- phase3: p = exp(e-m) once per pair, wave sum ----
  float lsum = 0.f;
  for (int k = lane; k < mycnt; k += 64) {
    float p = __expf(mypairs[k].x - m);
    mypairs[k].x = p;
    lsum += p;
  }
  for (int off = 32; off; off >>= 1) lsum += __shfl_down(lsum, off);
  if (lane == 0) red2[wave] = lsum;
  // no barrier needed: gather below reads only this wave's own segment

  // ---- gather: half-wave per pair, 4-deep unroll ----
  const int half = lane >> 5, lq = lane & 31;
  const float4* __restrict__ Wh4 = (const float4*)Wh;
  float ax = 0.f, ay = 0.f, az = 0.f, aw = 0.f;
  const int nit = (mycnt + 1) >> 1;
  int it = 0;
  for (; it + 3 < nit; it += 4) {
#pragma unroll
    for (int c = 0; c < 4; ++c) {
      int p = 2 * (it + c) + half;
      bool ok = p < mycnt;
      float2 pr = mypairs[ok ? p : 0];
      int j = ((const int*)&pr)[1];
      float4 v = Wh4[((size_t)j << 5) + lq];
      float w = ok ? pr.x - em : 0.f;
      ax += w * v.x; ay += w * v.y; az += w * v.z; aw += w * v.w;
    }
  }
  for (; it < nit; ++it) {
    int p = 2 * it + half;
    bool ok = p < mycnt;
    float2 pr = mypairs[ok ? p : 0];
    int j = ((const int*)&pr)[1];
    float4 v = Wh4[((size_t)j << 5) + lq];
    float w = ok ? pr.x - em : 0.f;
    ax += w * v.x; ay += w * v.y; az += w * v.z; aw += w * v.w;
  }
  // combine odd/even halves (same features, disjoint neighbor subsets)
  ax += __shfl_down(ax, 32);
  ay += __shfl_down(ay, 32);
  az += __shfl_down(az, 32);
  aw += __shfl_down(aw, 32);
  if (lane < 32)
    *(float4*)&fpart[wave][4 * lq] = make_float4(ax, ay, az, aw);
  __syncthreads();
  if (t < FDIM) {
    float l = red2[0] + red2[1] + red2[2] + red2[3]
              + (float)(N_NODES - cnt) * em;
    float o = (fpart[0][t] + fpart[1][t] + fpart[2][t] + fpart[3][t]
               + em * S[t]) / l;
    out[(size_t)i * FDIM + t] = o;
  }
}

extern "C" void kernel_launch(void* const* d_in, const int* in_sizes, int n_in,
                              void* d_out, int out_size, void* d_ws, size_t ws_size,
                              hipStream_t stream) {
  const float* h   = (const float*)d_in[0];
  const float* adj = (const float*)d_in[1];
  const float* W   = (const float*)d_in[2];
  const float* a   = (const float*)d_in[3];
  float* out = (float*)d_out;
  // workspace layout (fp32): Wh[N*F] | s1[N] | s2[N] | S[F]
  float* Wh = (float*)d_ws;
  float* s1 = Wh + (size_t)N_NODES * FDIM;
  float* s2 = s1 + N_NODES;
  float* S  = s2 + N_NODES;

  hipMemsetAsync(S, 0, FDIM * sizeof(float), stream);
  hipLaunchKernelGGL(wh_fused_kernel, dim3(N_NODES / 32), dim3(256), 0, stream,
                     h, W, Wh, S);
  hipLaunchKernelGGL(scores_kernel, dim3(N_NODES / 4), dim3(256), 0, stream,
                     Wh, a, s1, s2);
  hipLaunchKernelGGL(gat_row_kernel, dim3(N_NODES), dim3(256), 0, stream,
                     adj, Wh, s1, s2, S, out);
}

// Round 2
// 404.106 us; speedup vs baseline: 1.1032x; 1.0643x over previous
//
#include <hip/hip_runtime.h>

#define N_NODES 8192
#define FDIM 128
#define NEG_SLOPE 0.2f
#define SEG 512   // per-wave neighbor capacity (mean ~102, huge headroom)

// float -> bf16 bits, round-to-nearest-even (values are all normal finite)
__device__ __forceinline__ unsigned int f2bf(float f) {
  unsigned int u = __float_as_uint(f);
  return (u + 0x7FFFu + ((u >> 16) & 1u)) >> 16;
}

// ---------------- Kernel A: Whb(bf16) = h @ W.T, colsum S, s1/s2 scores ----
// fp32 Wh is never materialized: the only consumers were scores (fused here,
// straight from the fp32 accumulators) and the gather (which now reads bf16).
__global__ __launch_bounds__(256) void wh_fused_kernel(
    const float* __restrict__ h, const float* __restrict__ W,
    const float* __restrict__ a,
    unsigned int* __restrict__ Whb,   // packed bf16x2: N rows x 64 uints
    float* __restrict__ s1, float* __restrict__ s2,
    float* __restrict__ S) {
  __shared__ float Wt[FDIM * 132];   // Wt[k*132+o] = W[o][k]
  __shared__ float rows[32 * 132];   // rows[r*132+k]; reused as colsum scratch
  const int t = threadIdx.x;
  const int base = blockIdx.x * 32;
  for (int it = 0; it < 64; ++it) {
    int idx = t + 256 * it;          // idx = o*128+k
    int o = idx >> 7, k = idx & 127;
    Wt[k * 132 + o] = W[idx];
  }
  for (int it = 0; it < 16; ++it) {
    int idx = t + 256 * it;          // idx = r*128+col
    int r = idx >> 7, col = idx & 127;
    rows[r * 132 + col] = h[(size_t)base * FDIM + idx];
  }
  __syncthreads();
  const int c4 = (t & 31) * 4;
  const int g = t >> 5;
  float acc[4][4];
#pragma unroll
  for (int rr = 0; rr < 4; ++rr)
#pragma unroll
    for (int cc = 0; cc < 4; ++cc) acc[rr][cc] = 0.f;
  for (int k = 0; k < FDIM; ++k) {
    float4 wv = *(const float4*)&Wt[k * 132 + c4];
    float rv[4];
#pragma unroll
    for (int rr = 0; rr < 4; ++rr) rv[rr] = rows[(4 * g + rr) * 132 + k];
#pragma unroll
    for (int rr = 0; rr < 4; ++rr) {
      acc[rr][0] += rv[rr] * wv.x;
      acc[rr][1] += rv[rr] * wv.y;
      acc[rr][2] += rv[rr] * wv.z;
      acc[rr][3] += rv[rr] * wv.w;
    }
  }
  // ---- bf16 store of Wh (gather operand; 2 MB total -> L2-resident) ----
#pragma unroll
  for (int rr = 0; rr < 4; ++rr) {
    int r = base + 4 * g + rr;
    unsigned int p0 = f2bf(acc[rr][0]) | (f2bf(acc[rr][1]) << 16);
    unsigned int p1 = f2bf(acc[rr][2]) | (f2bf(acc[rr][3]) << 16);
    *(uint2*)&Whb[(size_t)r * 64 + (c4 >> 1)] = make_uint2(p0, p1);
  }
  // ---- fused scores: s1 = Wh@a1, s2 = Wh@a2 (half-wave shfl tree) ----
  {
    float4 a1v = *(const float4*)&a[c4];
    float4 a2v = *(const float4*)&a[FDIM + c4];
#pragma unroll
    for (int rr = 0; rr < 4; ++rr) {
      float d1 = acc[rr][0] * a1v.x + acc[rr][1] * a1v.y +
                 acc[rr][2] * a1v.z + acc[rr][3] * a1v.w;
      float d2 = acc[rr][0] * a2v.x + acc[rr][1] * a2v.y +
                 acc[rr][2] * a2v.z + acc[rr][3] * a2v.w;
#pragma unroll
      for (int off = 16; off; off >>= 1) {
        d1 += __shfl_down(d1, off);
        d2 += __shfl_down(d2, off);
      }
      if ((t & 31) == 0) {
        s1[base + 4 * g + rr] = d1;
        s2[base + 4 * g + rr] = d2;
      }
    }
  }
  __syncthreads();
  float4 cs = make_float4(acc[0][0] + acc[1][0] + acc[2][0] + acc[3][0],
                          acc[0][1] + acc[1][1] + acc[2][1] + acc[3][1],
                          acc[0][2] + acc[1][2] + acc[2][2] + acc[3][2],
                          acc[0][3] + acc[1][3] + acc[2][3] + acc[3][3]);
  *(float4*)&rows[g * FDIM + c4] = cs;
  __syncthreads();
  if (t < FDIM) {
    float s = 0.f;
#pragma unroll
    for (int gg = 0; gg < 8; ++gg) s += rows[gg * FDIM + t];
    atomicAdd(&S[t], s);
  }
}

// non-temporal float4 load: adj is streamed exactly once — keep it out of
// the L2 working set so Whb (2 MB) stays resident for the gather phase.
__device__ __forceinline__ float4 ntload4(const float4* p) {
  typedef float f4v __attribute__((ext_vector_type(4)));
  f4v v = __builtin_nontemporal_load((const f4v*)p);
  return make_float4(v[0], v[1], v[2], v[3]);
}

// ---------------- Kernel B: per-row softmax + sparse gather ----------------
// one block (4 waves) per row i.
// scan:   adj ONLY. 8 float4 loads forced in flight; ballot compaction.
// phase2: e = leakyrelu(s1i + s2[j]) via random 4B gathers, wave max.
// phase3: p = exp(e-m) once per pair, wave sum.
// gather: half-wave per pair, bf16 rows (256 B each, 8 B/lane), 4-deep unroll.
__global__ __launch_bounds__(256, 4) void gat_row_kernel(
    const float* __restrict__ adj, const unsigned int* __restrict__ Whb,
    const float* __restrict__ s1, const float* __restrict__ s2,
    const float* __restrict__ S, float* __restrict__ out) {
  const int i = blockIdx.x;
  const int t = threadIdx.x;
  const int lane = t & 63;
  const int wave = t >> 6;
  __shared__ float2 pairs[4 * SEG];  // .x = e then p ; .y = j (int bits)
  __shared__ int counts[4];
  __shared__ float red[4];           // per-wave max
  __shared__ float red2[4];          // per-wave exp-sum
  __shared__ float fpart[4][FDIM];

  const float s1i = s1[i];
  const float4* __restrict__ arow = (const float4*)(adj + (size_t)i * N_NODES);
  float2* __restrict__ mypairs = pairs + wave * SEG;
  const unsigned long long lmask = (1ull << lane) - 1ull;

  // ---- scan: all 8 row-chunks in flight, index-only compaction ----
  float4 av[8];
#pragma unroll
  for (int it = 0; it < 8; ++it) av[it] = ntload4(&arow[it * 256 + t]);
  asm volatile("" ::
      "v"(av[0].x), "v"(av[0].y), "v"(av[0].z), "v"(av[0].w),
      "v"(av[1].x), "v"(av[1].y), "v"(av[1].z), "v"(av[1].w),
      "v"(av[2].x), "v"(av[2].y), "v"(av[2].z), "v"(av[2].w),
      "v"(av[3].x), "v"(av[3].y), "v"(av[3].z), "v"(av[3].w),
      "v"(av[4].x), "v"(av[4].y), "v"(av[4].z), "v"(av[4].w),
      "v"(av[5].x), "v"(av[5].y), "v"(av[5].z), "v"(av[5].w),
      "v"(av[6].x), "v"(av[6].y), "v"(av[6].z), "v"(av[6].w),
      "v"(av[7].x), "v"(av[7].y), "v"(av[7].z), "v"(av[7].w));
  __builtin_amdgcn_sched_barrier(0);
  int cbase = 0;
#pragma unroll
  for (int it = 0; it < 8; ++it) {
    const int j4 = it * 256 + t;
    float v[4] = {av[it].x, av[it].y, av[it].z, av[it].w};
#pragma unroll
    for (int c = 0; c < 4; ++c) {
      bool pred = (v[c] != 0.f);
      unsigned long long b = __ballot(pred);
      if (pred) {
        int pos = cbase + (int)__popcll(b & lmask);
        if (pos < SEG) ((int*)&mypairs[pos])[1] = j4 * 4 + c;
      }
      cbase += (int)__popcll(b);
    }
  }
  const int mycnt = cbase < SEG ? cbase : SEG;
  if (lane == 0) counts[wave] = mycnt;

  // ---- phase2: e from s2[j] gathers, wave max ----
  float lmax = -1e30f;
  for (int k = lane; k < mycnt; k += 64) {
    int j = ((const int*)&mypairs[k])[1];
    float e = s1i + s2[j];
    e = e > 0.f ? e : NEG_SLOPE * e;
    mypairs[k].x = e;
    lmax = fmaxf(lmax, e);
  }
  for (int off = 32; off; off >>= 1) lmax = fmaxf(lmax, __shfl_down(lmax, off));
  if (lane == 0) red[wave] = lmax;
  __syncthreads();
  const int cnt = counts[0] + counts[1] + counts[2] + counts[3];
  float m = fmaxf(fmaxf(red[0], red[1]), fmaxf(red[2], red[3]));
  if (cnt < N_NODES) m = fmaxf(m, 0.f);  // adj==0 entries contribute z=0
  const float em = __expf(-m);

  // ---- phase3: p = exp(e-m) once per pair, wave sum ----
  float lsum = 0.f;
  for (int k = lane; k < mycnt; k += 64) {
    float p = __expf(mypairs[k].x - m);
    mypairs[k].x = p;
    lsum += p;
  }
  for (int off = 32; off; off >>= 1) lsum += __shfl_down(lsum, off);
  if (lane == 0) red2[wave] = lsum;
  // no barrier needed: gather below reads only this wave's own segment

  // ---- gather: half-wave per pair, bf16 rows, 4-deep unroll ----
  const int half = lane >> 5, lq = lane & 31;
  const uint2* __restrict__ Whb2 = (const uint2*)Whb;  // 32 x uint2 per row
  float ax = 0.f, ay = 0.f, az = 0.f, aw = 0.f;
  const int nit = (mycnt + 1) >> 1;
  int it = 0;
  for (; it + 3 < nit; it += 4) {
#pragma unroll
    for (int c = 0; c < 4; ++c) {
      int p = 2 * (it + c) + half;
      bool ok = p < mycnt;
      float2 pr = mypairs[ok ? p : 0];
      int j = ((const int*)&pr)[1];
      uint2 d = Whb2[((size_t)j << 5) + lq];
      float w = ok ? pr.x - em : 0.f;
      ax += w * __uint_as_float(d.x << 16);
      ay += w * __uint_as_float(d.x & 0xffff0000u);
      az += w * __uint_as_float(d.y << 16);
      aw += w * __uint_as_float(d.y & 0xffff0000u);
    }
  }
  for (; it < nit; ++it) {
    int p = 2 * it + half;
    bool ok = p < mycnt;
    float2 pr = mypairs[ok ? p : 0];
    int j = ((const int*)&pr)[1];
    uint2 d = Whb2[((size_t)j << 5) + lq];
    float w = ok ? pr.x - em : 0.f;
    ax += w * __uint_as_float(d.x << 16);
    ay += w * __uint_as_float(d.x & 0xffff0000u);
    az += w * __uint_as_float(d.y << 16);
    aw += w * __uint_as_float(d.y & 0xffff0000u);
  }
  // combine odd/even halves (same features, disjoint neighbor subsets)
  ax += __shfl_down(ax, 32);
  ay += __shfl_down(ay, 32);
  az += __shfl_down(az, 32);
  aw += __shfl_down(aw, 32);
  if (lane < 32)
    *(float4*)&fpart[wave][4 * lq] = make_float4(ax, ay, az, aw);
  __syncthreads();
  if (t < FDIM) {
    float l = red2[0] + red2[1] + red2[2] + red2[3]
              + (float)(N_NODES - cnt) * em;
    float o = (fpart[0][t] + fpart[1][t] + fpart[2][t] + fpart[3][t]
               + em * S[t]) / l;
    out[(size_t)i * FDIM + t] = o;
  }
}

extern "C" void kernel_launch(void* const* d_in, const int* in_sizes, int n_in,
                              void* d_out, int out_size, void* d_ws, size_t ws_size,
                              hipStream_t stream) {
  const float* h   = (const float*)d_in[0];
  const float* adj = (const float*)d_in[1];
  const float* W   = (const float*)d_in[2];
  const float* a   = (const float*)d_in[3];
  float* out = (float*)d_out;
  // workspace layout: Whb(bf16, N*64 uints = 2 MB) | s1[N] | s2[N] | S[F]
  unsigned int* Whb = (unsigned int*)d_ws;
  float* s1 = (float*)(Whb + (size_t)N_NODES * 64);
  float* s2 = s1 + N_NODES;
  float* S  = s2 + N_NODES;

  hipMemsetAsync(S, 0, FDIM * sizeof(float), stream);
  hipLaunchKernelGGL(wh_fused_kernel, dim3(N_NODES / 32), dim3(256), 0, stream,
                     h, W, a, Whb, s1, s2, S);
  hipLaunchKernelGGL(gat_row_kernel, dim3(N_NODES), dim3(256), 0, stream,
                     adj, Whb, s1, s2, S, out);
}